// Round 2
// baseline (324.532 us; speedup 1.0000x reference)
//
#include <hip/hip_runtime.h>

// B=8, L=512, K=512, D=M=N=P=64, all fp32.
// ws layout: vkc (8*512*64 = 1 MB) | wts (8*512*512 = 8 MB)

// ---------------------------------------------------------------------------
// K1: even blocks -> vkc[b,k,n] = sum_p vk[b,k,p,n]*vexp[b,k,p]  (stream 67MB)
//     odd  blocks -> weights[b,l,k] = softmax_k(scale * q.k)      (compute)
// Interleaved so every CU runs one stream-bound and one VALU-bound block set.
// ---------------------------------------------------------------------------
__global__ __launch_bounds__(256) void fused_pre(const float* __restrict__ q,
                                                 const float* __restrict__ k,
                                                 const float* __restrict__ vk,
                                                 const float* __restrict__ vexp,
                                                 const float* __restrict__ scale_p,
                                                 float* __restrict__ vkc,
                                                 float* __restrict__ wts) {
    const int t = threadIdx.x;
    const int wv = t >> 6, lane = t & 63;
    const int type = (gridDim.x > 1024) ? (blockIdx.x & 1) : 0;
    const int id   = (gridDim.x > 1024) ? (blockIdx.x >> 1) : blockIdx.x;

    if (type == 0) {
        // ---- vkc: one wave per (b,k) row; 16 hoisted float4 loads ----
        const int row = (id << 2) + wv;               // b*512 + kk
        const float ve = vexp[row * 64 + lane];       // lane p holds vexp[p]
        const int n0 = (lane & 15) << 2;
        const int p0 = lane >> 4;
        const float* base = vk + (long)row * 4096;
        float4 v[16];
        #pragma unroll
        for (int it = 0; it < 16; ++it)
            v[it] = *(const float4*)(base + (p0 + (it << 2)) * 64 + n0);
        float ax = 0.f, ay = 0.f, az = 0.f, aw = 0.f;
        #pragma unroll
        for (int it = 0; it < 16; ++it) {
            const float w = __shfl(ve, p0 + (it << 2), 64);
            ax += v[it].x * w; ay += v[it].y * w; az += v[it].z * w; aw += v[it].w * w;
        }
        ax += __shfl_down(ax, 32, 64); ax += __shfl_down(ax, 16, 64);
        ay += __shfl_down(ay, 32, 64); ay += __shfl_down(ay, 16, 64);
        az += __shfl_down(az, 32, 64); az += __shfl_down(az, 16, 64);
        aw += __shfl_down(aw, 32, 64); aw += __shfl_down(aw, 16, 64);
        if ((lane & 48) == 0) {
            float4 r; r.x = ax; r.y = ay; r.z = az; r.w = aw;
            *(float4*)(vkc + row * 64 + n0) = r;
        }
    } else {
        // ---- scores + softmax for (batch, 4 l-rows) ----
        __shared__ float q_s[256];
        __shared__ float sc[4][512];
        const int batch = id >> 7;
        const int l0 = (id & 127) << 2;
        const float scale = scale_p[0];

        q_s[t] = q[(batch * 512 + l0) * 64 + t];
        __syncthreads();

        const float* kb = k + batch * 512 * 64;
        const float4* q4 = (const float4*)q_s;
        #pragma unroll
        for (int it = 0; it < 2; ++it) {
            const int kk = t + (it << 8);
            const float4* krow = (const float4*)(kb + kk * 64);
            float a0 = 0.f, a1 = 0.f, a2 = 0.f, a3 = 0.f;
            #pragma unroll
            for (int dc = 0; dc < 16; ++dc) {
                const float4 kv = krow[dc];
                const float4 p0 = q4[dc], p1 = q4[16 + dc], p2 = q4[32 + dc], p3 = q4[48 + dc];
                a0 += p0.x * kv.x + p0.y * kv.y + p0.z * kv.z + p0.w * kv.w;
                a1 += p1.x * kv.x + p1.y * kv.y + p1.z * kv.z + p1.w * kv.w;
                a2 += p2.x * kv.x + p2.y * kv.y + p2.z * kv.z + p2.w * kv.w;
                a3 += p3.x * kv.x + p3.y * kv.y + p3.z * kv.z + p3.w * kv.w;
            }
            sc[0][kk] = scale * a0;
            sc[1][kk] = scale * a1;
            sc[2][kk] = scale * a2;
            sc[3][kk] = scale * a3;
        }
        __syncthreads();

        // softmax over K for l = wv; write weights straight to global
        float v[8]; float mx = -1e30f;
        #pragma unroll
        for (int j = 0; j < 8; ++j) { v[j] = sc[wv][lane + 64 * j]; mx = fmaxf(mx, v[j]); }
        #pragma unroll
        for (int off = 32; off; off >>= 1) mx = fmaxf(mx, __shfl_xor(mx, off, 64));
        float s = 0.f;
        #pragma unroll
        for (int j = 0; j < 8; ++j) { v[j] = __expf(v[j] - mx); s += v[j]; }
        #pragma unroll
        for (int off = 32; off; off >>= 1) s += __shfl_xor(s, off, 64);
        const float inv = 1.0f / s;
        float* wrow = wts + (batch * 512 + l0 + wv) * 512;
        #pragma unroll
        for (int j = 0; j < 8; ++j) wrow[lane + 64 * j] = v[j] * inv;
    }
}

// ---------------------------------------------------------------------------
// K2: per (batch, 2 l-rows), 128 threads (2 waves):
//   tmp = w @ vkc (k-split over waves) -> attn = vq @ tmp -> residual+LN
// vq loads are issued FIRST so the 67 MB stream's latency hides behind tmp.
// ---------------------------------------------------------------------------
__global__ __launch_bounds__(128) void fused_post(const float* __restrict__ q,
                                                  const float* __restrict__ vq,
                                                  const float* __restrict__ vkc,
                                                  const float* __restrict__ wts,
                                                  const float* __restrict__ gamma,
                                                  const float* __restrict__ beta,
                                                  float* __restrict__ out) {
    __shared__ float w_s[2 * 512];     // weights for 2 l-rows
    __shared__ float tp[2][2][64];     // per-wave partial tmp
    __shared__ float tmp_s[2][64];
    __shared__ float attn_s[2][64];

    const int t = threadIdx.x, wv = t >> 6, lane = t & 63;
    const int batch = blockIdx.x >> 8;
    const int l0 = (blockIdx.x & 255) << 1;
    const int row = batch * 512 + l0 + wv;          // this wave's l-row

    // ---- issue the big streaming loads immediately ----
    const float* vql = vq + (long)row * 4096;
    float4 v[16];
    #pragma unroll
    for (int it = 0; it < 16; ++it)
        v[it] = *(const float4*)(vql + it * 256 + lane * 4);   // 1 KB/wave-instr
    const float qreg = q[row * 64 + lane];

    // ---- stage weights (2x512 floats) into LDS ----
    const float* wg = wts + (batch * 512 + l0) * 512;
    #pragma unroll
    for (int i = 0; i < 2; ++i)
        *(float4*)(w_s + t * 4 + i * 512) = *(const float4*)(wg + t * 4 + i * 512);
    __syncthreads();

    // ---- tmp[l][n] = sum_k w[l][k] * vkc[b][k][n]; wave wv covers 256 k ----
    const float* vkcb = vkc + batch * 512 * 64;
    float a0 = 0.f, a1 = 0.f;
    const int kbeg = wv << 8;
    #pragma unroll 16
    for (int kk = kbeg; kk < kbeg + 256; ++kk) {
        const float vv = vkcb[kk * 64 + lane];      // coalesced 256B, L2-hot
        a0 += w_s[kk] * vv;                         // LDS broadcast
        a1 += w_s[512 + kk] * vv;
    }
    tp[wv][0][lane] = a0; tp[wv][1][lane] = a1;
    __syncthreads();
    tmp_s[wv][lane] = tp[0][wv][lane] + tp[1][wv][lane];
    // tmp_s[wv] / attn_s[wv] are produced+consumed by the same wave: no barrier

    // ---- attn[l][m] = sum_n vq[b,l,m,n] * tmp[l][n] ----
    const int n0 = (lane & 15) << 2;
    const float4 t4 = *(const float4*)&tmp_s[wv][n0];
    #pragma unroll
    for (int it = 0; it < 16; ++it) {
        float part = v[it].x * t4.x + v[it].y * t4.y + v[it].z * t4.z + v[it].w * t4.w;
        part += __shfl_down(part, 8, 16);
        part += __shfl_down(part, 4, 16);
        part += __shfl_down(part, 2, 16);
        part += __shfl_down(part, 1, 16);
        if ((lane & 15) == 0) attn_s[wv][it * 4 + (lane >> 4)] = part;
    }

    // ---- residual + LayerNorm over D=64 ----
    const float x = qreg + attn_s[wv][lane];
    float s1 = x, s2 = x * x;
    #pragma unroll
    for (int off = 32; off; off >>= 1) {
        s1 += __shfl_xor(s1, off, 64);
        s2 += __shfl_xor(s2, off, 64);
    }
    const float mean = s1 * (1.0f / 64.0f);
    const float var = s2 * (1.0f / 64.0f) - mean * mean;
    const float r = rsqrtf(var + 1e-3f);
    out[row * 64 + lane] = (x - mean) * r * gamma[lane] + beta[lane];
}

// ---------------------------------------------------------------------------
// Fallback (proven round-1 kernel) if ws is too small for the weights buffer.
// ---------------------------------------------------------------------------
__global__ __launch_bounds__(256) void attn_fallback(const float* __restrict__ q,
                                                     const float* __restrict__ k,
                                                     const float* __restrict__ vq,
                                                     const float* __restrict__ vkc,
                                                     const float* __restrict__ scale_p,
                                                     const float* __restrict__ gamma,
                                                     const float* __restrict__ beta,
                                                     float* __restrict__ out) {
    __shared__ float q_s[256];
    __shared__ float sc[4][512];
    __shared__ float tmpp[4][4][64];
    __shared__ float tmp_s[4][64];
    __shared__ float attn_s[4][64];
    const int t = threadIdx.x, wave = t >> 6, lane = t & 63;
    const int batch = blockIdx.x >> 7, l0 = (blockIdx.x & 127) * 4;
    const float scale = scale_p[0];
    q_s[t] = q[(batch * 512 + l0) * 64 + t];
    __syncthreads();
    {
        const float* kb = k + batch * 512 * 64;
        const float4* q4 = (const float4*)q_s;
        for (int it = 0; it < 2; ++it) {
            const int kk = t + it * 256;
            const float4* krow = (const float4*)(kb + kk * 64);
            float a0 = 0.f, a1 = 0.f, a2 = 0.f, a3 = 0.f;
            #pragma unroll
            for (int dc = 0; dc < 16; ++dc) {
                const float4 kv = krow[dc];
                const float4 p0 = q4[dc], p1 = q4[16 + dc], p2 = q4[32 + dc], p3 = q4[48 + dc];
                a0 += p0.x * kv.x + p0.y * kv.y + p0.z * kv.z + p0.w * kv.w;
                a1 += p1.x * kv.x + p1.y * kv.y + p1.z * kv.z + p1.w * kv.w;
                a2 += p2.x * kv.x + p2.y * kv.y + p2.z * kv.z + p2.w * kv.w;
                a3 += p3.x * kv.x + p3.y * kv.y + p3.z * kv.z + p3.w * kv.w;
            }
            sc[0][kk] = scale * a0; sc[1][kk] = scale * a1;
            sc[2][kk] = scale * a2; sc[3][kk] = scale * a3;
        }
    }
    __syncthreads();
    {
        float v[8]; float mx = -1e30f;
        #pragma unroll
        for (int j = 0; j < 8; ++j) { v[j] = sc[wave][lane + 64 * j]; mx = fmaxf(mx, v[j]); }
        #pragma unroll
        for (int off = 32; off; off >>= 1) mx = fmaxf(mx, __shfl_xor(mx, off, 64));
        float s = 0.f;
        #pragma unroll
        for (int j = 0; j < 8; ++j) { v[j] = __expf(v[j] - mx); s += v[j]; }
        #pragma unroll
        for (int off = 32; off; off >>= 1) s += __shfl_xor(s, off, 64);
        const float inv = 1.0f / s;
        #pragma unroll
        for (int j = 0; j < 8; ++j) sc[wave][lane + 64 * j] = v[j] * inv;
    }
    __syncthreads();
    {
        const float* vkcb = vkc + batch * 512 * 64;
        float a0 = 0.f, a1 = 0.f, a2 = 0.f, a3 = 0.f;
        for (int kk = wave * 128; kk < wave * 128 + 128; ++kk) {
            const float vv = vkcb[kk * 64 + lane];
            a0 += sc[0][kk] * vv; a1 += sc[1][kk] * vv;
            a2 += sc[2][kk] * vv; a3 += sc[3][kk] * vv;
        }
        tmpp[wave][0][lane] = a0; tmpp[wave][1][lane] = a1;
        tmpp[wave][2][lane] = a2; tmpp[wave][3][lane] = a3;
    }
    __syncthreads();
    tmp_s[wave][lane] = tmpp[0][wave][lane] + tmpp[1][wave][lane] +
                        tmpp[2][wave][lane] + tmpp[3][wave][lane];
    __syncthreads();
    {
        const float* vql = vq + (long)(batch * 512 + l0 + wave) * 4096;
        const int n0 = (lane & 15) << 2;
        const float4 t4 = *(const float4*)&tmp_s[wave][n0];
        #pragma unroll
        for (int it = 0; it < 16; ++it) {
            const float4 v4 = *(const float4*)(vql + it * 256 + lane * 4);
            float part = v4.x * t4.x + v4.y * t4.y + v4.z * t4.z + v4.w * t4.w;
            part += __shfl_down(part, 8, 16);
            part += __shfl_down(part, 4, 16);
            part += __shfl_down(part, 2, 16);
            part += __shfl_down(part, 1, 16);
            if ((lane & 15) == 0) attn_s[wave][it * 4 + (lane >> 4)] = part;
        }
    }
    {
        const float x = q_s[wave * 64 + lane] + attn_s[wave][lane];
        float s1 = x, s2 = x * x;
        #pragma unroll
        for (int off = 32; off; off >>= 1) { s1 += __shfl_xor(s1, off, 64); s2 += __shfl_xor(s2, off, 64); }
        const float mean = s1 * (1.0f / 64.0f);
        const float var = s2 * (1.0f / 64.0f) - mean * mean;
        const float r = rsqrtf(var + 1e-3f);
        out[(batch * 512 + l0 + wave) * 64 + lane] = (x - mean) * r * gamma[lane] + beta[lane];
    }
}

extern "C" void kernel_launch(void* const* d_in, const int* in_sizes, int n_in,
                              void* d_out, int out_size, void* d_ws, size_t ws_size,
                              hipStream_t stream) {
    const float* q     = (const float*)d_in[0];
    const float* k     = (const float*)d_in[1];
    const float* vq    = (const float*)d_in[2];
    const float* vk    = (const float*)d_in[3];
    const float* vexp  = (const float*)d_in[4];
    const float* scale = (const float*)d_in[5];
    const float* gamma = (const float*)d_in[6];
    const float* beta  = (const float*)d_in[7];
    float* out = (float*)d_out;

    float* vkc = (float*)d_ws;                         // 1 MB
    const size_t need = (size_t)(8 * 512 * 64 + 8 * 512 * 512) * sizeof(float); // 9 MB

    if (ws_size >= need) {
        float* wts = vkc + 8 * 512 * 64;               // 8 MB
        fused_pre<<<2048, 256, 0, stream>>>(q, k, vk, vexp, scale, vkc, wts);
        fused_post<<<2048, 128, 0, stream>>>(q, vq, vkc, wts, gamma, beta, out);
    } else {
        fused_pre<<<1024, 256, 0, stream>>>(q, k, vk, vexp, scale, vkc, nullptr);
        attn_fallback<<<1024, 256, 0, stream>>>(q, k, vq, vkc, scale, gamma, beta, out);
    }
}

// Round 3
// 231.530 us; speedup vs baseline: 1.4017x; 1.4017x over previous
//
#include <hip/hip_runtime.h>

// B=8, L=512, K=512, D=M=N=P=64, all fp32.
// ws: vkc = 8*512*64 floats (1 MB)

// ---------------------------------------------------------------------------
// K1 (proven R1): vkc[b,k,n] = sum_p vk[b,k,p,n] * vexp[b,k,p]
// One wave per (b,k) row; coalesced 1 KB float4 wave-loads; ~stream floor.
// ---------------------------------------------------------------------------
__global__ __launch_bounds__(256) void vkc_kernel(const float* __restrict__ vk,
                                                  const float* __restrict__ vexp,
                                                  float* __restrict__ vkc) {
    const int wave = (blockIdx.x << 2) + (threadIdx.x >> 6);  // b*512 + k
    const int lane = threadIdx.x & 63;

    const float ve_reg = vexp[wave * 64 + lane];   // lane p holds vexp[p]
    const int n0 = (lane & 15) << 2;
    const float* base = vk + (long)wave * 4096;

    float ax = 0.f, ay = 0.f, az = 0.f, aw = 0.f;
    #pragma unroll
    for (int it = 0; it < 16; ++it) {
        const int p = (lane >> 4) + (it << 2);
        const float4 v4 = *(const float4*)(base + p * 64 + n0);
        const float w = __shfl(ve_reg, p, 64);
        ax += v4.x * w; ay += v4.y * w; az += v4.z * w; aw += v4.w * w;
    }
    ax += __shfl_down(ax, 32, 64); ax += __shfl_down(ax, 16, 64);
    ay += __shfl_down(ay, 32, 64); ay += __shfl_down(ay, 16, 64);
    az += __shfl_down(az, 32, 64); az += __shfl_down(az, 16, 64);
    aw += __shfl_down(aw, 32, 64); aw += __shfl_down(aw, 16, 64);

    if ((lane & 48) == 0) {
        float4 r; r.x = ax; r.y = ay; r.z = az; r.w = aw;
        *(float4*)(vkc + wave * 64 + n0) = r;
    }
}

// ---------------------------------------------------------------------------
// K2: per (batch, 2 l-rows), 256 threads, 2048 blocks (8/CU nominal):
//   scores -> softmax -> tmp = w @ vkc (float4 loads) -> attn = vq.tmp -> LN
// ---------------------------------------------------------------------------
__global__ __launch_bounds__(256) void attn_kernel(const float* __restrict__ q,
                                                   const float* __restrict__ k,
                                                   const float* __restrict__ vq,
                                                   const float* __restrict__ vkc,
                                                   const float* __restrict__ scale_p,
                                                   const float* __restrict__ gamma,
                                                   const float* __restrict__ beta,
                                                   float* __restrict__ out) {
    __shared__ float q_s[2 * 64];         // 2 q rows
    __shared__ float sc[2][512];          // scores -> weights (in place)
    __shared__ float tp[4][2][64];        // per-wave partial tmp
    __shared__ float tmp_s[2][64];        // reduced tmp
    __shared__ float attn_s[2][64];       // attn output

    const int t = threadIdx.x;
    const int wv = t >> 6;
    const int lane = t & 63;
    const int batch = blockIdx.x >> 8;            // 256 blocks per batch
    const int l0 = (blockIdx.x & 255) << 1;       // 2 l-rows per block

    const float scale = scale_p[0];

    // ---- phase 0: stage 2 q rows (coalesced) ----
    if (t < 128) q_s[t] = q[(batch * 512 + l0) * 64 + t];
    __syncthreads();

    // ---- phase 1: scores[l][kk] = scale * dot(q[l], k[kk]); 2 kk per thread --
    {
        const float* kb = k + batch * 512 * 64;
        const float4* q4 = (const float4*)q_s;
        #pragma unroll
        for (int rep = 0; rep < 2; ++rep) {
            const int kk = t + (rep << 8);
            const float4* krow = (const float4*)(kb + kk * 64);
            float a0 = 0.f, a1 = 0.f;
            #pragma unroll
            for (int dc = 0; dc < 16; ++dc) {
                const float4 kv = krow[dc];                 // 1 KB/wave-instr
                const float4 p0 = q4[dc];                   // LDS broadcast
                const float4 p1 = q4[16 + dc];
                a0 += p0.x * kv.x + p0.y * kv.y + p0.z * kv.z + p0.w * kv.w;
                a1 += p1.x * kv.x + p1.y * kv.y + p1.z * kv.z + p1.w * kv.w;
            }
            sc[0][kk] = scale * a0;
            sc[1][kk] = scale * a1;
        }
    }
    __syncthreads();

    // ---- phase 2: softmax over K; wave 0 -> l=0, wave 1 -> l=1 ----
    if (wv < 2) {
        float v[8]; float mx = -1e30f;
        #pragma unroll
        for (int j = 0; j < 8; ++j) { v[j] = sc[wv][lane + 64 * j]; mx = fmaxf(mx, v[j]); }
        #pragma unroll
        for (int off = 32; off; off >>= 1) mx = fmaxf(mx, __shfl_xor(mx, off, 64));
        float s = 0.f;
        #pragma unroll
        for (int j = 0; j < 8; ++j) { v[j] = __expf(v[j] - mx); s += v[j]; }
        #pragma unroll
        for (int off = 32; off; off >>= 1) s += __shfl_xor(s, off, 64);
        const float inv = 1.0f / s;
        #pragma unroll
        for (int j = 0; j < 8; ++j) sc[wv][lane + 64 * j] = v[j] * inv;
    }
    __syncthreads();

    // ---- phase 3: tmp[l][n] = sum_k w[l][k]*vkc[b][k][n]; float4 vkc loads --
    {
        const float* vkcb = vkc + batch * 512 * 64;
        const int ksub = lane >> 4;                 // 4 k-rows per pass
        const int n0 = (lane & 15) << 2;
        float4 a0 = {0.f, 0.f, 0.f, 0.f}, a1 = {0.f, 0.f, 0.f, 0.f};
        const int kbeg = wv << 7;                   // 128 k per wave
        #pragma unroll 8
        for (int i = 0; i < 32; ++i) {
            const int kk = kbeg + (i << 2) + ksub;
            const float4 v4 = *(const float4*)(vkcb + kk * 64 + n0);  // 1 KB/instr
            const float w0 = sc[0][kk];             // 4-addr LDS, conflict-free
            const float w1 = sc[1][kk];
            a0.x += w0 * v4.x; a0.y += w0 * v4.y; a0.z += w0 * v4.z; a0.w += w0 * v4.w;
            a1.x += w1 * v4.x; a1.y += w1 * v4.y; a1.z += w1 * v4.z; a1.w += w1 * v4.w;
        }
        // reduce over the 4 ksub groups (lanes l, l+16, l+32, l+48)
        a0.x += __shfl_down(a0.x, 32, 64); a0.x += __shfl_down(a0.x, 16, 64);
        a0.y += __shfl_down(a0.y, 32, 64); a0.y += __shfl_down(a0.y, 16, 64);
        a0.z += __shfl_down(a0.z, 32, 64); a0.z += __shfl_down(a0.z, 16, 64);
        a0.w += __shfl_down(a0.w, 32, 64); a0.w += __shfl_down(a0.w, 16, 64);
        a1.x += __shfl_down(a1.x, 32, 64); a1.x += __shfl_down(a1.x, 16, 64);
        a1.y += __shfl_down(a1.y, 32, 64); a1.y += __shfl_down(a1.y, 16, 64);
        a1.z += __shfl_down(a1.z, 32, 64); a1.z += __shfl_down(a1.z, 16, 64);
        a1.w += __shfl_down(a1.w, 32, 64); a1.w += __shfl_down(a1.w, 16, 64);
        if (lane < 16) {
            *(float4*)&tp[wv][0][lane << 2] = a0;
            *(float4*)&tp[wv][1][lane << 2] = a1;
        }
    }
    __syncthreads();
    if (t < 128) {
        const int l = t >> 6, n = t & 63;
        tmp_s[l][n] = tp[0][l][n] + tp[1][l][n] + tp[2][l][n] + tp[3][l][n];
    }
    __syncthreads();

    // ---- phase 4: attn[l][m] = sum_n vq[b,l,m,n]*tmp[l][n]; 2 waves per l --
    {
        const int l = wv >> 1;
        const int half = wv & 1;                    // 8 m-groups per wave
        const float* vql = vq + (long)(batch * 512 + l0 + l) * 4096;
        const int n0 = (lane & 15) << 2;
        const float4 t4 = *(const float4*)&tmp_s[l][n0];
        #pragma unroll
        for (int it = 0; it < 8; ++it) {
            const int itg = (half << 3) + it;
            const float4 v4 = *(const float4*)(vql + itg * 256 + lane * 4); // 1 KB
            float part = v4.x * t4.x + v4.y * t4.y + v4.z * t4.z + v4.w * t4.w;
            part += __shfl_down(part, 8, 16);
            part += __shfl_down(part, 4, 16);
            part += __shfl_down(part, 2, 16);
            part += __shfl_down(part, 1, 16);
            if ((lane & 15) == 0) attn_s[l][(itg << 2) + (lane >> 4)] = part;
        }
    }
    __syncthreads();

    // ---- phase 5: residual + LayerNorm; wave 0 -> l=0, wave 1 -> l=1 ----
    if (wv < 2) {
        const float x = q_s[wv * 64 + lane] + attn_s[wv][lane];
        float s1 = x, s2 = x * x;
        #pragma unroll
        for (int off = 32; off; off >>= 1) {
            s1 += __shfl_xor(s1, off, 64);
            s2 += __shfl_xor(s2, off, 64);
        }
        const float mean = s1 * (1.0f / 64.0f);
        const float var = s2 * (1.0f / 64.0f) - mean * mean;
        const float r = rsqrtf(var + 1e-3f);
        out[(batch * 512 + l0 + wv) * 64 + lane] =
            (x - mean) * r * gamma[lane] + beta[lane];
    }
}

extern "C" void kernel_launch(void* const* d_in, const int* in_sizes, int n_in,
                              void* d_out, int out_size, void* d_ws, size_t ws_size,
                              hipStream_t stream) {
    const float* q     = (const float*)d_in[0];
    const float* k     = (const float*)d_in[1];
    const float* vq    = (const float*)d_in[2];
    const float* vk    = (const float*)d_in[3];
    const float* vexp  = (const float*)d_in[4];
    const float* scale = (const float*)d_in[5];
    const float* gamma = (const float*)d_in[6];
    const float* beta  = (const float*)d_in[7];
    float* out = (float*)d_out;
    float* vkc = (float*)d_ws;   // 1 MB

    vkc_kernel<<<1024, 256, 0, stream>>>(vk, vexp, vkc);
    attn_kernel<<<2048, 256, 0, stream>>>(q, k, vq, vkc, scale, gamma, beta, out);
}

// Round 4
// 186.117 us; speedup vs baseline: 1.7437x; 1.2440x over previous
//
#include <hip/hip_runtime.h>

// B=8, L=512, K=512, D=M=N=P=64, all fp32.
// ws: vkc = 8*512*64 floats (1 MB)

// ---------------------------------------------------------------------------
// K1 (proven): vkc[b,k,n] = sum_p vk[b,k,p,n] * vexp[b,k,p]
// One wave per (b,k) row; coalesced 1 KB float4 wave-loads; ~stream floor.
// ---------------------------------------------------------------------------
__global__ __launch_bounds__(256) void vkc_kernel(const float* __restrict__ vk,
                                                  const float* __restrict__ vexp,
                                                  float* __restrict__ vkc) {
    const int wave = (blockIdx.x << 2) + (threadIdx.x >> 6);  // b*512 + k
    const int lane = threadIdx.x & 63;

    const float ve_reg = vexp[wave * 64 + lane];   // lane p holds vexp[p]
    const int n0 = (lane & 15) << 2;
    const float* base = vk + (long)wave * 4096;

    float ax = 0.f, ay = 0.f, az = 0.f, aw = 0.f;
    #pragma unroll
    for (int it = 0; it < 16; ++it) {
        const int p = (lane >> 4) + (it << 2);
        const float4 v4 = *(const float4*)(base + p * 64 + n0);
        const float w = __shfl(ve_reg, p, 64);
        ax += v4.x * w; ay += v4.y * w; az += v4.z * w; aw += v4.w * w;
    }
    ax += __shfl_down(ax, 32, 64); ax += __shfl_down(ax, 16, 64);
    ay += __shfl_down(ay, 32, 64); ay += __shfl_down(ay, 16, 64);
    az += __shfl_down(az, 32, 64); az += __shfl_down(az, 16, 64);
    aw += __shfl_down(aw, 32, 64); aw += __shfl_down(aw, 16, 64);

    if ((lane & 48) == 0) {
        float4 r; r.x = ax; r.y = ay; r.z = az; r.w = aw;
        *(float4*)(vkc + wave * 64 + n0) = r;
    }
}

// ---------------------------------------------------------------------------
// K2: per (batch, 8 l-rows), 512 threads (8 waves), 512 blocks:
//   scores -> softmax -> tmp = w @ vkc (float4, 8-chain ILP) -> vq.tmp -> LN
// ---------------------------------------------------------------------------
__global__ __launch_bounds__(512) void attn_kernel(const float* __restrict__ q,
                                                   const float* __restrict__ k,
                                                   const float* __restrict__ vq,
                                                   const float* __restrict__ vkc,
                                                   const float* __restrict__ scale_p,
                                                   const float* __restrict__ gamma,
                                                   const float* __restrict__ beta,
                                                   float* __restrict__ out) {
    __shared__ float q_s[8 * 64];         // 8 q rows (2 KB)
    __shared__ float sc[8][512];          // scores -> weights (16 KB)
    __shared__ float tp[8][8][64];        // per-wave partial tmp (16 KB)
    __shared__ float tmp_s[8 * 64];       // reduced tmp (2 KB)
    __shared__ float attn_s[8][64];       // attn outputs (2 KB)

    const int t = threadIdx.x;
    const int wv = t >> 6;                // 0..7
    const int lane = t & 63;
    const int batch = blockIdx.x >> 6;    // 64 blocks per batch
    const int l0 = (blockIdx.x & 63) << 3;// 8 l-rows per block

    const float scale = scale_p[0];

    // ---- phase 0: stage 8 q rows (512 consecutive floats, coalesced) ----
    q_s[t] = q[(batch * 512 + l0) * 64 + t];
    __syncthreads();

    // ---- phase 1: thread t owns k-row kk=t; 8 l-dots, 8 independent chains --
    {
        const float4* krow = (const float4*)(k + (batch * 512 + t) * 64);
        const float4* q4 = (const float4*)q_s;
        float acc[8] = {0.f, 0.f, 0.f, 0.f, 0.f, 0.f, 0.f, 0.f};
        #pragma unroll
        for (int dc = 0; dc < 16; ++dc) {
            const float4 kv = krow[dc];
            #pragma unroll
            for (int l = 0; l < 8; ++l) {
                const float4 p = q4[l * 16 + dc];   // wave-uniform: LDS broadcast
                acc[l] += p.x * kv.x + p.y * kv.y + p.z * kv.z + p.w * kv.w;
            }
        }
        #pragma unroll
        for (int l = 0; l < 8; ++l) sc[l][t] = scale * acc[l];  // coalesced LDS
    }
    __syncthreads();

    // ---- phase 2: softmax over K=512; wave wv handles l=wv ----
    {
        float v[8]; float mx = -1e30f;
        #pragma unroll
        for (int j = 0; j < 8; ++j) { v[j] = sc[wv][lane + 64 * j]; mx = fmaxf(mx, v[j]); }
        #pragma unroll
        for (int off = 32; off; off >>= 1) mx = fmaxf(mx, __shfl_xor(mx, off, 64));
        float s = 0.f;
        #pragma unroll
        for (int j = 0; j < 8; ++j) { v[j] = __expf(v[j] - mx); s += v[j]; }
        #pragma unroll
        for (int off = 32; off; off >>= 1) s += __shfl_xor(s, off, 64);
        const float inv = 1.0f / s;
        #pragma unroll
        for (int j = 0; j < 8; ++j) sc[wv][lane + 64 * j] = v[j] * inv;
    }
    __syncthreads();

    // ---- phase 3: tmp[l][n] = sum_k w[l][k]*vkc[b][k][n]; wave covers 64 k --
    {
        const float* vkcb = vkc + batch * 512 * 64;
        const int ksub = lane >> 4;               // 4 k-rows per float4 pass
        const int n0 = (lane & 15) << 2;
        const int kbeg = wv << 6;                 // 64 k per wave
        float4 a[8];
        #pragma unroll
        for (int l = 0; l < 8; ++l) { a[l].x = 0.f; a[l].y = 0.f; a[l].z = 0.f; a[l].w = 0.f; }
        #pragma unroll
        for (int i = 0; i < 16; ++i) {
            const int kk = kbeg + (i << 2) + ksub;
            const float4 v4 = *(const float4*)(vkcb + kk * 64 + n0);  // 1 KB/instr
            #pragma unroll
            for (int l = 0; l < 8; ++l) {
                const float w = sc[l][kk];        // 4-addr b32, conflict-free
                a[l].x += w * v4.x; a[l].y += w * v4.y;
                a[l].z += w * v4.z; a[l].w += w * v4.w;
            }
        }
        // reduce over the 4 ksub groups (lanes l, l+16, l+32, l+48)
        #pragma unroll
        for (int l = 0; l < 8; ++l) {
            a[l].x += __shfl_down(a[l].x, 32, 64); a[l].x += __shfl_down(a[l].x, 16, 64);
            a[l].y += __shfl_down(a[l].y, 32, 64); a[l].y += __shfl_down(a[l].y, 16, 64);
            a[l].z += __shfl_down(a[l].z, 32, 64); a[l].z += __shfl_down(a[l].z, 16, 64);
            a[l].w += __shfl_down(a[l].w, 32, 64); a[l].w += __shfl_down(a[l].w, 16, 64);
        }
        if (lane < 16) {
            #pragma unroll
            for (int l = 0; l < 8; ++l)
                *(float4*)&tp[wv][l][lane << 2] = a[l];
        }
    }
    __syncthreads();
    {   // reduce the 8 wave partials; t = l*64 + n
        float s = tp[0][wv][lane];
        #pragma unroll
        for (int w = 1; w < 8; ++w) s += tp[w][wv][lane];
        tmp_s[t] = s;
    }
    __syncthreads();

    // ---- phase 4: attn[l][m] = sum_n vq[b,l,m,n]*tmp[l][n]; wave wv -> l=wv --
    {
        const float* vql = vq + (long)(batch * 512 + l0 + wv) * 4096;
        const int n0 = (lane & 15) << 2;
        const float4 t4 = *(const float4*)&tmp_s[wv * 64 + n0];
        #pragma unroll
        for (int it = 0; it < 16; ++it) {
            const float4 v4 = *(const float4*)(vql + it * 256 + lane * 4); // 1 KB
            float part = v4.x * t4.x + v4.y * t4.y + v4.z * t4.z + v4.w * t4.w;
            part += __shfl_down(part, 8, 16);
            part += __shfl_down(part, 4, 16);
            part += __shfl_down(part, 2, 16);
            part += __shfl_down(part, 1, 16);
            if ((lane & 15) == 0) attn_s[wv][it * 4 + (lane >> 4)] = part;
        }
    }
    // attn_s[wv] produced+consumed by the same wave -> no barrier

    // ---- phase 5: residual + LayerNorm over D=64; wave wv -> l=wv ----
    {
        const float x = q_s[wv * 64 + lane] + attn_s[wv][lane];
        float s1 = x, s2 = x * x;
        #pragma unroll
        for (int off = 32; off; off >>= 1) {
            s1 += __shfl_xor(s1, off, 64);
            s2 += __shfl_xor(s2, off, 64);
        }
        const float mean = s1 * (1.0f / 64.0f);
        const float var = s2 * (1.0f / 64.0f) - mean * mean;
        const float r = rsqrtf(var + 1e-3f);
        out[(batch * 512 + l0 + wv) * 64 + lane] =
            (x - mean) * r * gamma[lane] + beta[lane];
    }
}

extern "C" void kernel_launch(void* const* d_in, const int* in_sizes, int n_in,
                              void* d_out, int out_size, void* d_ws, size_t ws_size,
                              hipStream_t stream) {
    const float* q     = (const float*)d_in[0];
    const float* k     = (const float*)d_in[1];
    const float* vq    = (const float*)d_in[2];
    const float* vk    = (const float*)d_in[3];
    const float* vexp  = (const float*)d_in[4];
    const float* scale = (const float*)d_in[5];
    const float* gamma = (const float*)d_in[6];
    const float* beta  = (const float*)d_in[7];
    float* out = (float*)d_out;
    float* vkc = (float*)d_ws;   // 1 MB

    vkc_kernel<<<1024, 256, 0, stream>>>(vk, vexp, vkc);
    attn_kernel<<<512, 512, 0, stream>>>(q, k, vq, vkc, scale, gamma, beta, out);
}